// Round 10
// baseline (175.928 us; speedup 1.0000x reference)
//
#include <hip/hip_runtime.h>
#include <math.h>

#define IN_DIM 1024
#define OUT_DIM 1024
#define NROWS 8192
#define XSTRIDE 1025   // x rows: 1024 feats + 1 phase

typedef __attribute__((ext_vector_type(8))) short bf16x8;
typedef __attribute__((ext_vector_type(4))) float f32x4;

static __device__ __forceinline__ unsigned f2bf(float f) {
  union { float f; unsigned u; } v; v.f = f;
  unsigned u = v.u;
  return (u + 0x7fffu + ((u >> 16) & 1u)) >> 16;  // RTNE
}

// ---- prep: unchanged.
//  blocks [0,2048):    W(4,1024,1024) f32 -> Wall bf16, row g=(o&15)|(k<<4)|((o>>4)<<6)
//  blocks [2048,10240): feats -> F bf16 (8192x1024); thread 0 also writes coef[b] (float4)
__global__ __launch_bounds__(256) void prep_kernel(
    const float* __restrict__ x, const float* __restrict__ W,
    unsigned short* __restrict__ Wb, unsigned short* __restrict__ F,
    float* __restrict__ coef)
{
  const int blk = blockIdx.x;
  if (blk < 2048) {
    const int t = blk * 256 + threadIdx.x;
    const int flat = t * 8;                    // 8 elems of W
    const int k = flat >> 20;
    const int o = (flat >> 10) & 1023;
    const int i = flat & 1023;                 // multiple of 8
    const float4 fa = *reinterpret_cast<const float4*>(W + flat);
    const float4 fb = *reinterpret_cast<const float4*>(W + flat + 4);
    uint4 pk;
    pk.x = f2bf(fa.x) | (f2bf(fa.y) << 16);
    pk.y = f2bf(fa.z) | (f2bf(fa.w) << 16);
    pk.z = f2bf(fb.x) | (f2bf(fb.y) << 16);
    pk.w = f2bf(fb.z) | (f2bf(fb.w) << 16);
    const int g = (o & 15) | (k << 4) | ((o >> 4) << 6);
    *reinterpret_cast<uint4*>(Wb + (size_t)g * 1024 + i) = pk;
  } else {
    const int b = blk - 2048;
    const float* xr = x + (size_t)b * XSTRIDE;
    const int i = threadIdx.x * 4;
    ushort4 vv;
    vv.x = (unsigned short)f2bf(xr[i]);     vv.y = (unsigned short)f2bf(xr[i + 1]);
    vv.z = (unsigned short)f2bf(xr[i + 2]); vv.w = (unsigned short)f2bf(xr[i + 3]);
    *reinterpret_cast<ushort4*>(F + (size_t)b * 1024 + i) = vv;
    if (threadIdx.x == 0) {
      const float ps = 4.0f * xr[IN_DIM];
      const int ip = (int)ps;            // trunc, ps in [0,4)
      const int i1 = ip & 3;
      const float mu = ps - (float)ip;
      const float mu2 = mu * mu, mu3 = mu2 * mu;
      const float c0 = -0.5f * mu3 +        mu2 - 0.5f * mu;
      const float c1 =  1.5f * mu3 - 2.5f * mu2 + 1.0f;
      const float c2 = -1.5f * mu3 + 2.0f * mu2 + 0.5f * mu;
      const float c3 =  0.5f * mu3 - 0.5f * mu2;
      const int d0 = (0-i1)&3, d1 = (1-i1)&3, d2 = (2-i1)&3, d3 = (3-i1)&3;
      float4 cv;
      cv.x = d0==0 ? c1 : d0==1 ? c2 : d0==2 ? c3 : c0;
      cv.y = d1==0 ? c1 : d1==1 ? c2 : d1==2 ? c3 : c0;
      cv.z = d2==0 ? c1 : d2==1 ? c2 : d2==2 ? c3 : c0;
      cv.w = d3==0 ? c1 : d3==1 ? c2 : d3==2 ? c3 : c0;
      *reinterpret_cast<float4*>(coef + (size_t)b * 4) = cv;
    }
  }
}

// ---- GEMM: C'(8192 x 4096) = F . Wall^T, fragment ni == knot, fused cubic+
// bias+elu epilogue, T1 XCD swizzle. TRUE T4 this time: BK=32 with THREE
// rotating LDS buffers (48 KB -> 3 blocks/CU). Iter t: stage tile t+2 into
// the buffer freed at t-1, compute tile t, then s_waitcnt vmcnt(4) -- tile
// t+1's 4 loads (issued one full iteration earlier, ~2 iters of cover) must
// have landed; tile t+2's 4 stay IN FLIGHT across the barrier. vmcnt drains
// to 0 exactly once (t=30). Round-9's failure was drain-to-0 every iter with
// only ~180cy of cover for ~500cy latency -> 300cy exposed x32.
#define BM 128
#define BN 128   // g-columns = 32 o's x 4 knots
#define BK 32

__global__ __launch_bounds__(256, 3) void gemm_kernel(
    const unsigned short* __restrict__ F,    // 8192x1024 bf16
    const unsigned short* __restrict__ Wb,   // 4096x1024 bf16, g-layout
    const float* __restrict__ coef,          // 8192x4 f32
    const float* __restrict__ bias,          // 4x1024 f32
    float* __restrict__ out)
{
  __shared__ unsigned short As[3][BM * BK];   // 3 x 8 KB
  __shared__ unsigned short Bs[3][BN * BK];   // 3 x 8 KB  (48 KB total)

  // T1: grid 32(x) x 64(y), x-major linear id; XCD c = lin%8 owns one 16x16 chunk.
  const int lin = blockIdx.y * 32 + blockIdx.x;
  const int xcd = lin & 7;
  const int idx = lin >> 3;                // 0..255 within chunk
  const int bx  = (xcd & 1) * 16 + (idx & 15);
  const int by  = (xcd >> 1) * 16 + (idx >> 4);

  const int tid  = threadIdx.x;
  const int wave = tid >> 6;
  const int lane = tid & 63;
  const int row0  = by * BM;
  const int col0g = bx * BN;               // g-row base of Wall

  // staging (64B rows): 4 threads/row; XOR chunk swizzle on global source.
  // m(r) = (r>>1)&3; r = srow + it*64 keeps m invariant.
  const int srow = tid >> 2;               // 0..63
  const int scc  = tid & 3;
  const int sgc  = (scc ^ ((srow >> 1) & 3)) * 8;

  const int wr = (wave >> 1) * 64;
  const int wc = (wave & 1) * 64;
  const int fm = lane & 15;
  const int fq = lane >> 4;
  // read chunk: fq ^ m(row); row parity in 2-row units -> m = (fm>>1)&3.
  // Bank check: 2-way max (free, m136). Verified 0 conflicts in round 9.
  const int lc = (fq ^ ((fm >> 1) & 3)) * 8;

  f32x4 acc[4][4];   // [mi][ni=knot]
  const f32x4 zero = {0.f, 0.f, 0.f, 0.f};
  #pragma unroll
  for (int a = 0; a < 4; a++)
    #pragma unroll
    for (int b = 0; b < 4; b++)
      acc[a][b] = zero;

  const unsigned short* Abase = F  + (size_t)row0  * 1024;
  const unsigned short* Bbase = Wb + (size_t)col0g * 1024;

#define STG(p, kb) do {                                                        \
    _Pragma("unroll")                                                          \
    for (int it_ = 0; it_ < 2; ++it_) {                                        \
      const int r_ = srow + it_ * 64;                                          \
      __builtin_amdgcn_global_load_lds(                                        \
        (const __attribute__((address_space(1))) void*)(                       \
            Abase + (size_t)r_ * 1024 + (kb) + sgc),                           \
        (__attribute__((address_space(3))) void*)(&As[p][r_ * BK + scc * 8]),  \
        16, 0, 0);                                                             \
      __builtin_amdgcn_global_load_lds(                                        \
        (const __attribute__((address_space(1))) void*)(                       \
            Bbase + (size_t)r_ * 1024 + (kb) + sgc),                           \
        (__attribute__((address_space(3))) void*)(&Bs[p][r_ * BK + scc * 8]),  \
        16, 0, 0);                                                             \
    } } while (0)

  // prologue: stage tiles 0,1 (4 VMEM ops each per thread)
  STG(0, 0);
  STG(1, BK);
  asm volatile("s_waitcnt vmcnt(4)" ::: "memory");   // tile0 landed; tile1 flying
  __builtin_amdgcn_s_barrier();

  int p = 0;                                // buffer holding tile t
  #pragma unroll 1
  for (int t = 0; t < 32; ++t) {
    const int q = (p >= 1) ? p - 1 : 2;     // (t+2)%3 == (p-1+3)%3
    if (t < 30) STG(q, (t + 2) * BK);       // into buffer freed at iter t-1

    bf16x8 af[4], bfr[4];
    #pragma unroll
    for (int mi = 0; mi < 4; mi++)
      af[mi] = *reinterpret_cast<const bf16x8*>(&As[p][(wr + mi * 16 + fm) * BK + lc]);
    #pragma unroll
    for (int ni = 0; ni < 4; ni++)
      bfr[ni] = *reinterpret_cast<const bf16x8*>(&Bs[p][(wc + ni * 16 + fm) * BK + lc]);
    #pragma unroll
    for (int mi = 0; mi < 4; mi++)
      #pragma unroll
      for (int ni = 0; ni < 4; ni++)
        acc[mi][ni] = __builtin_amdgcn_mfma_f32_16x16x32_bf16(
            af[mi], bfr[ni], acc[mi][ni], 0, 0, 0);

    // counted wait: tile t+1's 4 loads (issued at iter t-1) must be done;
    // tile t+2's 4 (issued above) remain in flight across the barrier.
    if (t < 30)       asm volatile("s_waitcnt vmcnt(4)" ::: "memory");
    else if (t == 30) asm volatile("s_waitcnt vmcnt(0)" ::: "memory");
    if (t < 31) __builtin_amdgcn_s_barrier();
    p = (p >= 2) ? 0 : p + 1;
  }
#undef STG

  // ---- epilogue: v = sum_k c_k*(acc_k + bias_k[o]); fast elu; dense store
  const int o = fm + 16 * (2 * bx + (wave & 1));   // this lane's output column
  const float b0 = bias[o];
  const float b1 = bias[OUT_DIM + o];
  const float b2 = bias[2 * OUT_DIM + o];
  const float b3 = bias[3 * OUT_DIM + o];
  #pragma unroll
  for (int mi = 0; mi < 4; mi++) {
    #pragma unroll
    for (int r = 0; r < 4; r++) {
      const int rloc = wr + mi * 16 + (fq << 2) + r;
      const float4 c = *reinterpret_cast<const float4*>(coef + (size_t)(row0 + rloc) * 4);
      float v = c.x * (acc[mi][0][r] + b0)
              + c.y * (acc[mi][1][r] + b1)
              + c.z * (acc[mi][2][r] + b2)
              + c.w * (acc[mi][3][r] + b3);
      // elu(alpha=1): exp(v)-1 via hw v_exp_f32; abs err ~1e-7 << 4.3e-3 threshold
      const float e = __expf(v) - 1.0f;
      v = (v > 0.0f) ? v : e;
      out[(size_t)(row0 + rloc) * OUT_DIM + o] = v;
    }
  }
}

extern "C" void kernel_launch(void* const* d_in, const int* in_sizes, int n_in,
                              void* d_out, int out_size, void* d_ws, size_t ws_size,
                              hipStream_t stream) {
  const float* x  = (const float*)d_in[0];   // (8192, 1025)
  const float* wk = (const float*)d_in[1];   // (4, 1024, 1024)
  const float* bk = (const float*)d_in[2];   // (4, 1024)
  float* out = (float*)d_out;                // (8192, 1024) fp32

  char* ws = (char*)d_ws;
  unsigned short* Wb = (unsigned short*)ws;                   // 8 MB
  unsigned short* F  = (unsigned short*)(ws + (8u << 20));    // 16 MB
  float* coef        = (float*)(ws + (24u << 20));            // 128 KB

  hipLaunchKernelGGL(prep_kernel, dim3(2048 + NROWS), dim3(256), 0, stream,
                     x, wk, Wb, F, coef);
  hipLaunchKernelGGL(gemm_kernel, dim3(4096 / BN, NROWS / BM), dim3(256), 0, stream,
                     F, Wb, coef, bk, out);
}

// Round 11
// 160.854 us; speedup vs baseline: 1.0937x; 1.0937x over previous
//
#include <hip/hip_runtime.h>
#include <math.h>

#define IN_DIM 1024
#define OUT_DIM 1024
#define NROWS 8192
#define XSTRIDE 1025   // x rows: 1024 feats + 1 phase

typedef __attribute__((ext_vector_type(8))) short bf16x8;
typedef __attribute__((ext_vector_type(4))) float f32x4;

static __device__ __forceinline__ unsigned f2bf(float f) {
  union { float f; unsigned u; } v; v.f = f;
  unsigned u = v.u;
  return (u + 0x7fffu + ((u >> 16) & 1u)) >> 16;  // RTNE
}

// ---- prep:
//  blocks [0,2048):    W(4,1024,1024) f32 -> Wall bf16, row g=(o&15)|(k<<4)|((o>>4)<<6)
//  blocks [2048,10240): feats -> F bf16 (8192x1024); thread 0 also writes coef[b] (float4)
__global__ __launch_bounds__(256) void prep_kernel(
    const float* __restrict__ x, const float* __restrict__ W,
    unsigned short* __restrict__ Wb, unsigned short* __restrict__ F,
    float* __restrict__ coef)
{
  const int blk = blockIdx.x;
  if (blk < 2048) {
    const int t = blk * 256 + threadIdx.x;
    const int flat = t * 8;                    // 8 elems of W
    const int k = flat >> 20;
    const int o = (flat >> 10) & 1023;
    const int i = flat & 1023;                 // multiple of 8
    const float4 fa = *reinterpret_cast<const float4*>(W + flat);
    const float4 fb = *reinterpret_cast<const float4*>(W + flat + 4);
    uint4 pk;
    pk.x = f2bf(fa.x) | (f2bf(fa.y) << 16);
    pk.y = f2bf(fa.z) | (f2bf(fa.w) << 16);
    pk.z = f2bf(fb.x) | (f2bf(fb.y) << 16);
    pk.w = f2bf(fb.z) | (f2bf(fb.w) << 16);
    const int g = (o & 15) | (k << 4) | ((o >> 4) << 6);
    *reinterpret_cast<uint4*>(Wb + (size_t)g * 1024 + i) = pk;
  } else {
    const int b = blk - 2048;
    const float* xr = x + (size_t)b * XSTRIDE;
    const int i = threadIdx.x * 4;
    ushort4 vv;
    vv.x = (unsigned short)f2bf(xr[i]);     vv.y = (unsigned short)f2bf(xr[i + 1]);
    vv.z = (unsigned short)f2bf(xr[i + 2]); vv.w = (unsigned short)f2bf(xr[i + 3]);
    *reinterpret_cast<ushort4*>(F + (size_t)b * 1024 + i) = vv;
    if (threadIdx.x == 0) {
      const float ps = 4.0f * xr[IN_DIM];
      const int ip = (int)ps;            // trunc, ps in [0,4)
      const int i1 = ip & 3;
      const float mu = ps - (float)ip;
      const float mu2 = mu * mu, mu3 = mu2 * mu;
      const float c0 = -0.5f * mu3 +        mu2 - 0.5f * mu;
      const float c1 =  1.5f * mu3 - 2.5f * mu2 + 1.0f;
      const float c2 = -1.5f * mu3 + 2.0f * mu2 + 0.5f * mu;
      const float c3 =  0.5f * mu3 - 0.5f * mu2;
      const int d0 = (0-i1)&3, d1 = (1-i1)&3, d2 = (2-i1)&3, d3 = (3-i1)&3;
      float4 cv;
      cv.x = d0==0 ? c1 : d0==1 ? c2 : d0==2 ? c3 : c0;
      cv.y = d1==0 ? c1 : d1==1 ? c2 : d1==2 ? c3 : c0;
      cv.z = d2==0 ? c1 : d2==1 ? c2 : d2==2 ? c3 : c0;
      cv.w = d3==0 ? c1 : d3==1 ? c2 : d3==2 ? c3 : c0;
      *reinterpret_cast<float4*>(coef + (size_t)b * 4) = cv;
    }
  }
}

// ---- GEMM: C'(8192 x 4096) = F . Wall^T, knots interleaved in N so that
// fragment ni == knot index; cubic combine + bias + elu fused per-lane in
// epilogue. Best measured configuration (round 8: gemm 66.7us, 1030 TF,
// MfmaUtil 46%, conflicts 0): 1-phase 2-barrier single-buffer loop,
// global_load_lds w16, chunk-XOR swizzle, 4 blocks/CU, + bijective
// XCD-aware 2D-chunk block swizzle (T1) -> FETCH_SIZE 74->62 MB.
// Structural ceiling evidence (rounds 1-10): all 8-phase/counted-vmcnt/
// 3-buffer/fat-tile/2-wave/32x32-pipe variants measured slower; the
// cross-block implicit overlap of this structure is the binding mechanism.
#define BM 128
#define BN 128   // g-columns = 32 o's x 4 knots
#define BK 64

__global__ __launch_bounds__(256, 4) void gemm_kernel(
    const unsigned short* __restrict__ F,    // 8192x1024 bf16
    const unsigned short* __restrict__ Wb,   // 4096x1024 bf16, g-layout
    const float* __restrict__ coef,          // 8192x4 f32
    const float* __restrict__ bias,          // 4x1024 f32
    float* __restrict__ out)
{
  __shared__ unsigned short As[BM * BK];   // 16 KB
  __shared__ unsigned short Bs[BN * BK];   // 16 KB  (32 KB total)

  // XCD swizzle: grid is 32(x) x 64(y) = 2048 blocks, default linear id is
  // x-major. Remap so XCD c (= lin%8 under round-robin dispatch) owns one
  // contiguous 16x16 tile chunk: c -> (cx,cy) = (c&1, c>>1).
  const int lin = blockIdx.y * 32 + blockIdx.x;
  const int xcd = lin & 7;
  const int idx = lin >> 3;                // 0..255 within chunk
  const int bx  = (xcd & 1) * 16 + (idx & 15);
  const int by  = (xcd >> 1) * 16 + (idx >> 4);

  const int tid  = threadIdx.x;
  const int wave = tid >> 6;
  const int lane = tid & 63;
  const int row0  = by * BM;
  const int col0g = bx * BN;               // g-row base of Wall

  // staging: thread t -> LDS slot t*16B; XOR chunk swizzle on global source
  const int srow = tid >> 3;
  const int scc  = tid & 7;
  const int sgc  = (scc ^ (srow & 7)) * 8;

  const int wr = (wave >> 1) * 64;
  const int wc = (wave & 1) * 64;
  const int fm = lane & 15;
  const int fq = lane >> 4;

  f32x4 acc[4][4];   // [mi][ni=knot]
  const f32x4 zero = {0.f, 0.f, 0.f, 0.f};
  #pragma unroll
  for (int a = 0; a < 4; a++)
    #pragma unroll
    for (int b = 0; b < 4; b++)
      acc[a][b] = zero;

  const unsigned short* Abase = F  + (size_t)row0  * 1024;
  const unsigned short* Bbase = Wb + (size_t)col0g * 1024;

  for (int kb = 0; kb < 1024; kb += BK) {
    #pragma unroll
    for (int it = 0; it < 4; it++) {
      const int r = srow + it * 32;   // (r&7)==(srow&7): swizzle invariant
      __builtin_amdgcn_global_load_lds(
          (const __attribute__((address_space(1))) void*)(Abase + (size_t)r * 1024 + kb + sgc),
          (__attribute__((address_space(3))) void*)(As + r * BK + scc * 8), 16, 0, 0);
      __builtin_amdgcn_global_load_lds(
          (const __attribute__((address_space(1))) void*)(Bbase + (size_t)r * 1024 + kb + sgc),
          (__attribute__((address_space(3))) void*)(Bs + r * BK + scc * 8), 16, 0, 0);
    }
    __syncthreads();

    #pragma unroll
    for (int kk = 0; kk < BK; kk += 32) {
      bf16x8 af[4], bfr[4];
      #pragma unroll
      for (int mi = 0; mi < 4; mi++) {
        const int r  = wr + mi * 16 + fm;
        const int lc = ((kk >> 3) + fq) ^ (fm & 7);
        af[mi] = *reinterpret_cast<const bf16x8*>(As + r * BK + lc * 8);
      }
      #pragma unroll
      for (int ni = 0; ni < 4; ni++) {
        const int r  = wc + ni * 16 + fm;
        const int lc = ((kk >> 3) + fq) ^ (fm & 7);
        bfr[ni] = *reinterpret_cast<const bf16x8*>(Bs + r * BK + lc * 8);
      }
      #pragma unroll
      for (int mi = 0; mi < 4; mi++)
        #pragma unroll
        for (int ni = 0; ni < 4; ni++)
          acc[mi][ni] = __builtin_amdgcn_mfma_f32_16x16x32_bf16(
              af[mi], bfr[ni], acc[mi][ni], 0, 0, 0);
    }
    __syncthreads();
  }

  // ---- epilogue: v = sum_k c_k*(acc_k + bias_k[o]); fast elu; dense store
  const int o = fm + 16 * (2 * bx + (wave & 1));   // this lane's output column
  const float b0 = bias[o];
  const float b1 = bias[OUT_DIM + o];
  const float b2 = bias[2 * OUT_DIM + o];
  const float b3 = bias[3 * OUT_DIM + o];
  #pragma unroll
  for (int mi = 0; mi < 4; mi++) {
    #pragma unroll
    for (int r = 0; r < 4; r++) {
      const int rloc = wr + mi * 16 + (fq << 2) + r;
      const float4 c = *reinterpret_cast<const float4*>(coef + (size_t)(row0 + rloc) * 4);
      float v = c.x * (acc[mi][0][r] + b0)
              + c.y * (acc[mi][1][r] + b1)
              + c.z * (acc[mi][2][r] + b2)
              + c.w * (acc[mi][3][r] + b3);
      // elu(alpha=1): exp(v)-1 via hw v_exp_f32; abs err ~1e-7 << 4.3e-3 threshold
      const float e = __expf(v) - 1.0f;
      v = (v > 0.0f) ? v : e;
      out[(size_t)(row0 + rloc) * OUT_DIM + o] = v;
    }
  }
}

extern "C" void kernel_launch(void* const* d_in, const int* in_sizes, int n_in,
                              void* d_out, int out_size, void* d_ws, size_t ws_size,
                              hipStream_t stream) {
  const float* x  = (const float*)d_in[0];   // (8192, 1025)
  const float* wk = (const float*)d_in[1];   // (4, 1024, 1024)
  const float* bk = (const float*)d_in[2];   // (4, 1024)
  float* out = (float*)d_out;                // (8192, 1024) fp32

  char* ws = (char*)d_ws;
  unsigned short* Wb = (unsigned short*)ws;                   // 8 MB
  unsigned short* F  = (unsigned short*)(ws + (8u << 20));    // 16 MB
  float* coef        = (float*)(ws + (24u << 20));            // 128 KB

  hipLaunchKernelGGL(prep_kernel, dim3(2048 + NROWS), dim3(256), 0, stream,
                     x, wk, Wb, F, coef);
  hipLaunchKernelGGL(gemm_kernel, dim3(4096 / BN, NROWS / BM), dim3(256), 0, stream,
                     F, Wb, coef, bk, out);
}